// Round 3
// baseline (348.682 us; speedup 1.0000x reference)
//
#include <hip/hip_runtime.h>
#include <hip/hip_bf16.h>
#include <stdint.h>

// EMASpitDelta: B=128, L=4096, H=64, V=64, HALF=32, ALPHA=0.95
// V=64 -> token pipeline collapses to a 64-entry table (kernel 1).
// Scan M <- M (I - b k k^T) + b h k^T is affine in M -> chunk-parallel:
// per chunk P = prod(A_t), U = scan-from-0; fold M <- M P_c + U_c (kernel 3).
// Scan layout (kernel 2): wave = (b, chunk, mat); lanes 0-31 = rows of P,
// lanes 32-63 = rows of U. k/token are wave-uniform -> scalar loads (SGPR),
// double-buffered; NO LDS, NO shuffles, in-lane 32-FMA dots.
// Inputs fp32 or bf16 (runtime-detected from gamma bit pattern).

#define BETA 0.05f
#define NB 128
#define NL 4096
#define NSTEPS 4095

__device__ __forceinline__ float ldf(const void* p, int i, int isbf) {
    return isbf ? __bfloat162float(((const __hip_bfloat16*)p)[i])
                : ((const float*)p)[i];
}

// ---------------- Kernel 1: per-token-value tables ----------------
// grid 64 (token v), block 64 (feature j). tbl (f32):
// [0..2047]=hs, [2048..4095]=ks(norm), [4096..6143]=he, [6144..8191]=ke
__global__ __launch_bounds__(64) void build_tables(
    const void* embed, const void* W1, const void* b1, const void* W2,
    const void* b2, const void* ln_g, const void* ln_b,
    const void* Ws, const void* bs, const void* We, const void* be,
    float* __restrict__ tbl)
{
    int v = blockIdx.x;
    int j = threadIdx.x;
    int isbf = (*(const uint32_t*)ln_g == 0x3F803F80u) ? 1 : 0;
    __shared__ float h0s[64];
    __shared__ float act[128];
    __shared__ float hrow[64];

    float h0 = ldf(embed, v * 64 + j, isbf);
    h0s[j] = h0;
    __syncthreads();

    float za = ldf(b1, j, isbf);
    float zb = ldf(b1, j + 64, isbf);
    for (int k = 0; k < 64; ++k) {
        float hk = h0s[k];
        za = fmaf(hk, ldf(W1, k * 128 + j, isbf), za);
        zb = fmaf(hk, ldf(W1, k * 128 + j + 64, isbf), zb);
    }
    act[j] = fmaxf(za, 0.0f);
    act[j + 64] = fmaxf(zb, 0.0f);
    __syncthreads();

    float ff = ldf(b2, j, isbf);
    for (int k = 0; k < 128; ++k)
        ff = fmaf(act[k], ldf(W2, k * 64 + j, isbf), ff);
    float x = h0 + ff;

    float s = x;
    for (int off = 32; off >= 1; off >>= 1) s += __shfl_xor(s, off, 64);
    float mu = s * (1.0f / 64.0f);
    float d = x - mu;
    float s2 = d * d;
    for (int off = 32; off >= 1; off >>= 1) s2 += __shfl_xor(s2, off, 64);
    float var = s2 * (1.0f / 64.0f);
    float h = d / sqrtf(var + 1e-5f) * ldf(ln_g, j, isbf) + ldf(ln_b, j, isbf);
    hrow[j] = h;
    __syncthreads();

    if (j < 32) {
        float sv = ldf(bs, j, isbf);
        for (int k = 0; k < 64; ++k)
            sv = fmaf(hrow[k], ldf(Ws, k * 32 + j, isbf), sv);
        float n2 = sv * sv;
        for (int off = 16; off >= 1; off >>= 1) n2 += __shfl_xor(n2, off, 64);
        float nrm = fmaxf(sqrtf(n2), 1e-12f);
        tbl[v * 32 + j] = sv;
        tbl[2048 + v * 32 + j] = sv / nrm;
    } else {
        int jj = j - 32;
        float ev = ldf(be, jj, isbf);
        for (int k = 0; k < 64; ++k)
            ev = fmaf(hrow[k], ldf(We, k * 32 + jj, isbf), ev);
        float n2 = ev * ev;
        for (int off = 16; off >= 1; off >>= 1) n2 += __shfl_xor(n2, off, 64);
        float nrm = fmaxf(sqrtf(n2), 1e-12f);
        tbl[4096 + v * 32 + jj] = ev;
        tbl[6144 + v * 32 + jj] = ev / nrm;
    }
}

// ---------------- Kernel 2: chunk scan, LDS-free, row-per-lane ------------
__device__ __forceinline__ void loadk(float4 (&k)[8], float& hr,
                                      const float* kt, const float* ht,
                                      int v, int r) {
    const float4* kp = (const float4*)(kt + v * 32);  // wave-uniform -> s_load
#pragma unroll
    for (int i = 0; i < 8; ++i) k[i] = kp[i];
    hr = ht[v * 32 + r];  // coalesced 128B vector load (U-half uses it)
}

__device__ __forceinline__ void scan_step(float (&R)[32], const float4 (&k)[8],
                                          float hr, float bsc, int uhalf) {
    float a0 = 0.f, a1 = 0.f, a2 = 0.f, a3 = 0.f;
#pragma unroll
    for (int jc = 0; jc < 8; ++jc) {
        a0 = fmaf(R[4 * jc + 0], k[jc].x, a0);
        a1 = fmaf(R[4 * jc + 1], k[jc].y, a1);
        a2 = fmaf(R[4 * jc + 2], k[jc].z, a2);
        a3 = fmaf(R[4 * jc + 3], k[jc].w, a3);
    }
    float dot = (a0 + a1) + (a2 + a3);
    float coefP = -bsc * dot;
    float coefU = bsc * (hr - dot);
    float coef = uhalf ? coefU : coefP;
#pragma unroll
    for (int jc = 0; jc < 8; ++jc) {
        R[4 * jc + 0] = fmaf(coef, k[jc].x, R[4 * jc + 0]);
        R[4 * jc + 1] = fmaf(coef, k[jc].y, R[4 * jc + 1]);
        R[4 * jc + 2] = fmaf(coef, k[jc].z, R[4 * jc + 2]);
        R[4 * jc + 3] = fmaf(coef, k[jc].w, R[4 * jc + 3]);
    }
}

__global__ __launch_bounds__(256) void chunk_scan(
    const int* __restrict__ seq, const float* __restrict__ tbl,
    float* __restrict__ PTbuf, float* __restrict__ Ubuf, int C, int CL)
{
    int halfC = C >> 1;
    int b = blockIdx.x / halfC;
    int rem = blockIdx.x % halfC;
    // wave id must be provably uniform so token/k loads become scalar:
    int q = __builtin_amdgcn_readfirstlane((int)(threadIdx.x >> 6));
    int idx = rem * 4 + q;      // in [0, 2C)
    int c = idx >> 1;
    int mat = idx & 1;
    int lane = threadIdx.x & 63;
    int r = lane & 31;
    int uhalf = lane >> 5;      // 0 = P rows, 1 = U rows

    const float* kt = tbl + 2048 + mat * 4096;  // ks or ke (normalized)
    const float* ht = tbl + mat * 4096;         // hs or he

    int t0 = c * CL;
    int clen = NSTEPS - t0;
    if (clen > CL) clen = CL;
    if (clen < 0) clen = 0;
    const int* sq = seq + b * NL + t0;

    float R[32];
#pragma unroll
    for (int j = 0; j < 32; ++j)
        R[j] = (uhalf == 0 && r == j) ? 1.0f : 0.0f;

    const float bstep = BETA * (1.0f / 4096.0f);

    float4 ka[8], kb[8];
    float ha = 0.f, hb = 0.f;
    int vc = (clen > 0) ? sq[0] : 0;
    loadk(ka, ha, kt, ht, vc, r);
    int vn = (clen > 1) ? sq[1] : vc;

    int it = 0;
    for (; it + 2 <= clen; it += 2) {
        int v2 = (it + 2 < clen) ? sq[it + 2] : vn;
        loadk(kb, hb, kt, ht, vn, r);                 // prefetch step it+1
        float bsc0 = mat ? (bstep * (float)(t0 + it + 1)) : BETA;
        scan_step(R, ka, ha, bsc0, uhalf);            // step it
        int v3 = (it + 3 < clen) ? sq[it + 3] : v2;
        loadk(ka, ha, kt, ht, v2, r);                 // prefetch step it+2
        float bsc1 = mat ? (bstep * (float)(t0 + it + 2)) : BETA;
        scan_step(R, kb, hb, bsc1, uhalf);            // step it+1
        vn = v3;
    }
    if (it < clen) {
        float bsc0 = mat ? (bstep * (float)(t0 + it + 1)) : BETA;
        scan_step(R, ka, ha, bsc0, uhalf);
    }

    size_t base = (((size_t)b * 2 + mat) * C + c) * 1024;
    if (uhalf == 0) {
        // P row r -> PT[col][row]: coalesced dword stores per col
#pragma unroll
        for (int j = 0; j < 32; ++j)
            PTbuf[base + j * 32 + r] = R[j];
    } else {
        float* ud = Ubuf + base + r * 32;
#pragma unroll
        for (int jc = 0; jc < 8; ++jc)
            *(float4*)(ud + 4 * jc) = make_float4(R[4 * jc + 0], R[4 * jc + 1],
                                                  R[4 * jc + 2], R[4 * jc + 3]);
    }
}

// ---------------- Kernel 3: fold chunks + readout + projections -----------
// grid = NB, block = 512 (team 0 = M_s with threads 0-255, team 1 = M_e).
// Per fold: Mnew = M * P + U with lane owning M[r][4q..4q+3].
__global__ __launch_bounds__(512) void fold_readout(
    const int* __restrict__ seq, const float* __restrict__ tbl,
    const float* __restrict__ PTbuf, const float* __restrict__ Ubuf,
    const void* Wrp, const void* brp, const void* Wout, const void* bout,
    const void* ln_g, void* __restrict__ outv, int C)
{
    __shared__ float Ml[2][32 * 36];
    __shared__ float Pl[2][32 * 36];
    __shared__ float rv[64];
    __shared__ float o1s[64];

    int b = blockIdx.x;
    int tid = threadIdx.x;
    int team = tid >> 8;
    int t = tid & 255;
    int r = t >> 3, cq = t & 7;
    int isbf = (*(const uint32_t*)ln_g == 0x3F803F80u) ? 1 : 0;

    for (int i = t; i < 32 * 36; i += 256) Ml[team][i] = 0.0f;
    __syncthreads();

    for (int cf = 0; cf < C; ++cf) {
        size_t base = (((size_t)b * 2 + team) * C + cf) * 1024;
        for (int i = t; i < 1024; i += 256)
            Pl[team][(i >> 5) * 36 + (i & 31)] = PTbuf[base + i];
        __syncthreads();

        float ax = 0.f, ay = 0.f, az = 0.f, aw = 0.f;
#pragma unroll
        for (int jc = 0; jc < 8; ++jc) {
            float4 m = *(const float4*)&Ml[team][r * 36 + 4 * jc];
            float4 p0 = *(const float4*)&Pl[team][(4 * cq + 0) * 36 + 4 * jc];
            float4 p1 = *(const float4*)&Pl[team][(4 * cq + 1) * 36 + 4 * jc];
            float4 p2 = *(const float4*)&Pl[team][(4 * cq + 2) * 36 + 4 * jc];
            float4 p3 = *(const float4*)&Pl[team][(4 * cq + 3) * 36 + 4 * jc];
            ax = fmaf(m.x, p0.x, ax); ax = fmaf(m.y, p0.y, ax);
            ax = fmaf(m.z, p0.z, ax); ax = fmaf(m.w, p0.w, ax);
            ay = fmaf(m.x, p1.x, ay); ay = fmaf(m.y, p1.y, ay);
            ay = fmaf(m.z, p1.z, ay); ay = fmaf(m.w, p1.w, ay);
            az = fmaf(m.x, p2.x, az); az = fmaf(m.y, p2.y, az);
            az = fmaf(m.z, p2.z, az); az = fmaf(m.w, p2.w, az);
            aw = fmaf(m.x, p3.x, aw); aw = fmaf(m.y, p3.y, aw);
            aw = fmaf(m.z, p3.z, aw); aw = fmaf(m.w, p3.w, aw);
        }
        float4 u = *(const float4*)&Ubuf[base + r * 32 + 4 * cq];
        __syncthreads();
        *(float4*)&Ml[team][r * 36 + 4 * cq] =
            make_float4(ax + u.x, ay + u.y, az + u.z, aw + u.w);
        __syncthreads();
    }

    // readout: r_m = M_m q_m, q = normalized table row of the last token
    int vlast = seq[b * NL + (NL - 1)];
    if (t < 32) {
        const float* qv = tbl + 2048 + team * 4096 + vlast * 32;
        float a0 = 0.f, a1 = 0.f, a2 = 0.f, a3 = 0.f;
#pragma unroll
        for (int jc = 0; jc < 8; ++jc) {
            float4 m = *(const float4*)&Ml[team][t * 36 + 4 * jc];
            a0 = fmaf(m.x, qv[4 * jc + 0], a0);
            a1 = fmaf(m.y, qv[4 * jc + 1], a1);
            a2 = fmaf(m.z, qv[4 * jc + 2], a2);
            a3 = fmaf(m.w, qv[4 * jc + 3], a3);
        }
        rv[team * 32 + t] = (a0 + a1) + (a2 + a3);
    }
    __syncthreads();
    if (tid < 64) {
        float o = ldf(brp, tid, isbf);
        for (int i = 0; i < 64; ++i)
            o = fmaf(rv[i], ldf(Wrp, i * 64 + tid, isbf), o);
        o1s[tid] = o;
    }
    __syncthreads();
    if (tid < 64) {
        float o = ldf(bout, tid, isbf);
        for (int i = 0; i < 64; ++i)
            o = fmaf(o1s[i], ldf(Wout, i * 64 + tid, isbf), o);
        if (isbf)
            ((__hip_bfloat16*)outv)[b * 64 + tid] = __float2bfloat16(o);
        else
            ((float*)outv)[b * 64 + tid] = o;
    }
}

extern "C" void kernel_launch(void* const* d_in, const int* in_sizes, int n_in,
                              void* d_out, int out_size, void* d_ws, size_t ws_size,
                              hipStream_t stream) {
    const int* seq = (const int*)d_in[0];
    const void* embed = d_in[1];
    const void* W1 = d_in[2];
    const void* b1 = d_in[3];
    const void* W2 = d_in[4];
    const void* b2 = d_in[5];
    const void* ln_g = d_in[6];
    const void* ln_b = d_in[7];
    const void* Ws = d_in[8];
    const void* bs = d_in[9];
    const void* We = d_in[10];
    const void* be = d_in[11];
    const void* Wrp = d_in[12];
    const void* brp = d_in[13];
    const void* Wout = d_in[14];
    const void* bout = d_in[15];

    // ws layout (floats): tbl[8192] | PTbuf[NB*2*C*1024] | Ubuf[same]
    float* tbl = (float*)d_ws;
    size_t avail_f = ws_size / 4;
    int C = 16;
    while (C > 4 && (size_t)8192 + (size_t)524288 * C > avail_f) C >>= 1;
    int CL = (NSTEPS + C - 1) / C;
    float* PTbuf = tbl + 8192;
    float* Ubuf = PTbuf + (size_t)NB * 2 * C * 1024;

    build_tables<<<64, 64, 0, stream>>>(embed, W1, b1, W2, b2, ln_g, ln_b,
                                        Ws, bs, We, be, tbl);
    chunk_scan<<<NB * (C / 2), 256, 0, stream>>>(seq, tbl, PTbuf, Ubuf, C, CL);
    fold_readout<<<NB, 512, 0, stream>>>(seq, tbl, PTbuf, Ubuf,
                                         Wrp, brp, Wout, bout, ln_g, d_out, C);
}